// Round 14
// baseline (108.765 us; speedup 1.0000x reference)
//
#include <hip/hip_runtime.h>

// MACE symmetric contraction (corr-3), N=2048, NL=16, C=128, E=10, P3=23, P2=4, P1=1.
// out[n,c] = sum_{a<=b<=i} A3[t,tri,c] x_a x_b x_i + sum_{a<=b} A2[t,pr,c] x_a x_b
//          + sum_a A1[t,a,c] x_a,  with A3 = U3sym @ W3[t] etc. (t = atom type).
// R14b: identical resubmit of R14 (bench infra failed twice; kernel audited
// clean — same precedent as R7->R9b). ONE variable vs R13: GG 4 -> 2.
// R13's rocprof caught k_main: 48us, VALUBusy 14%, Occupancy 20%, zero scratch
// -> LATENCY-bound at grid-limited occupancy. GG=2 doubles the grid to
// ~12 blocks/CU (~24 waves/CU) to cover the ~200cy L2 w4-load chain.
// Frozen eval_nest body; live set shrinks (xv 64->32 regs), spill risk down.

constexpr int NL = 16;
constexpr int CC = 128;
constexpr int EE = 10;
constexpr int P3 = 23;
constexpr int P2 = 4;
constexpr int P1 = 1;
constexpr int NTRI = 816;   // C(18,3): a<=b<=i from 16
constexpr int NPAIR = 136;  // C(17,2): a<=b from 16
constexpr int GG = 2;       // atoms per group (R14: was 4)
constexpr int S1 = 4;       // nest split: a in [0,4) | [4,8) | [8,16)
constexpr int S2 = 8;

constexpr int pairsBefore(int a) {
    int s = 0;
    for (int x = 0; x < a; x++) s += NL - x;
    return s;
}
constexpr int trisBefore(int a) {
    int s = 0;
    for (int x = 0; x < a; x++) s += (NL - x) * (NL - x + 1) / 2;
    return s;
}
static_assert(trisBefore(S1) % 4 == 0, "tri split1 must be float4-aligned");
static_assert(pairsBefore(S1) % 2 == 0, "pair split1 must be float2-aligned");
static_assert(trisBefore(S2) % 4 == 0, "tri split2 must be float4-aligned");
static_assert(pairsBefore(S2) % 2 == 0, "pair split2 must be float2-aligned");

// ---------------- Fused precompute + bucketing ----------------
// Block roles: [0, NB3)        A3 build (16 tris each, symU inline via LDS)
//              [NB3, +NB2)     A2 build (8 pairs each, float2-interleaved out)
//              [.., +EE)       A1 build (one type)
//              last block      atom bucketing/grouping
__global__ void k_pre(const float* __restrict__ U3, const float* __restrict__ U2,
                      const float* __restrict__ U1,
                      const float* __restrict__ W3, const float* __restrict__ W2,
                      const float* __restrict__ W1,
                      const int* __restrict__ types,
                      float* __restrict__ A3, float* __restrict__ A2,
                      float* __restrict__ A1,
                      int* __restrict__ buckets, int* __restrict__ groups,
                      int* __restrict__ ngroups, int N) {
    constexpr int TB = 16;                  // tris per A3 block
    constexpr int PB = 8;                   // pairs per A2 block
    constexpr int NB3 = EE * (NTRI / TB);   // 510
    constexpr int NB2 = EE * (NPAIR / PB);  // 170
    __shared__ float u3l[TB * P3];
    __shared__ float u2l[PB * P2];
    __shared__ int scnt[EE];
    __shared__ int goff[EE + 1];
    int b = blockIdx.x;
    int tid = threadIdx.x;

    if (b < NB3) {
        int t = b / (NTRI / TB), tri16 = b % (NTRI / TB);
        for (int idx = tid; idx < TB * P3; idx += blockDim.x) {
            int lt = idx / P3, k = idx % P3;
            int tri = tri16 * TB + lt;
            int rem = tri, a = 0;
            while (rem >= (NL - a) * (NL - a + 1) / 2) { rem -= (NL - a) * (NL - a + 1) / 2; a++; }
            int bb = a;
            while (rem >= NL - bb) { rem -= NL - bb; bb++; }
            int i = bb + rem;
            auto u = [&](int p, int q, int r) { return U3[((p * NL + q) * NL + r) * P3 + k]; };
            float s = u(a,bb,i) + u(a,i,bb) + u(bb,a,i) + u(bb,i,a) + u(i,a,bb) + u(i,bb,a);
            int m = (a == bb && bb == i) ? 6 : ((a == bb || bb == i) ? 2 : 1);
            u3l[idx] = s / (float)m;
        }
        __syncthreads();
        int c = tid;
        float4 sv[TB / 4];
        #pragma unroll
        for (int j = 0; j < TB / 4; j++) sv[j] = {0.f, 0.f, 0.f, 0.f};
        #pragma unroll
        for (int k = 0; k < P3; k++) {
            float w = W3[(t * P3 + k) * CC + c];
            #pragma unroll
            for (int j = 0; j < TB / 4; j++) {
                sv[j].x += u3l[(j * 4 + 0) * P3 + k] * w;
                sv[j].y += u3l[(j * 4 + 1) * P3 + k] * w;
                sv[j].z += u3l[(j * 4 + 2) * P3 + k] * w;
                sv[j].w += u3l[(j * 4 + 3) * P3 + k] * w;
            }
        }
        #pragma unroll
        for (int j = 0; j < TB / 4; j++)
            ((float4*)A3)[((size_t)t * (NTRI / 4) + tri16 * (TB / 4) + j) * CC + c] = sv[j];
    } else if (b < NB3 + NB2) {
        int j = b - NB3;
        int t = j / (NPAIR / PB), pr8 = j % (NPAIR / PB);
        for (int idx = tid; idx < PB * P2; idx += blockDim.x) {
            int lp = idx / P2, k = idx % P2;
            int pr = pr8 * PB + lp;
            int rem = pr, a = 0;
            while (rem >= NL - a) { rem -= NL - a; a++; }
            int bb = a + rem;
            float s = U2[(a * NL + bb) * P2 + k];
            if (a != bb) s += U2[(bb * NL + a) * P2 + k];
            u2l[idx] = s;
        }
        __syncthreads();
        int c = tid;
        float2 sv[PB / 2];
        #pragma unroll
        for (int jj = 0; jj < PB / 2; jj++) sv[jj] = {0.f, 0.f};
        #pragma unroll
        for (int k = 0; k < P2; k++) {
            float w = W2[(t * P2 + k) * CC + c];
            #pragma unroll
            for (int jj = 0; jj < PB / 2; jj++) {
                sv[jj].x += u2l[(jj * 2 + 0) * P2 + k] * w;
                sv[jj].y += u2l[(jj * 2 + 1) * P2 + k] * w;
            }
        }
        #pragma unroll
        for (int jj = 0; jj < PB / 2; jj++)
            ((float2*)A2)[((size_t)t * (NPAIR / 2) + pr8 * (PB / 2) + jj) * CC + c] = sv[jj];
    } else if (b < NB3 + NB2 + EE) {
        int t = b - NB3 - NB2;
        int c = tid;
        #pragma unroll
        for (int a = 0; a < NL; a++) {
            // P1 == 1: A1[t,a,c] = U1[a] * W1[t,0,c]
            A1[((size_t)t * NL + a) * CC + c] = U1[a * P1] * W1[(size_t)t * P1 * CC + c];
        }
    } else {
        // ---- bucketing / grouping (single block) ----
        if (tid < EE) scnt[tid] = 0;
        __syncthreads();
        for (int n = tid; n < N; n += blockDim.x) {
            int t = types[n];
            int pos = atomicAdd(&scnt[t], 1);
            buckets[t * N + pos] = n;
        }
        __syncthreads();
        if (tid == 0) {
            int off = 0;
            for (int t = 0; t < EE; t++) { goff[t] = off; off += (scnt[t] + GG - 1) / GG; }
            goff[EE] = off;
            *ngroups = off;
        }
        __syncthreads();
        for (int t = 0; t < EE; t++) {
            int cnt = scnt[t];
            int ng = (cnt + GG - 1) / GG;
            for (int g = tid; g < ng; g += blockDim.x) {
                int* gr = &groups[(goff[t] + g) * 8];
                int nv = cnt - g * GG; if (nv > GG) nv = GG;
                gr[0] = t;
                gr[5] = nv;
                for (int j = 0; j < GG; j++) {
                    int jj = j < nv ? j : nv - 1;
                    gr[1 + j] = buckets[t * N + g * GG + jj];
                }
            }
        }
    }
}

// ---------------- Main: evaluate cubic form per (group-slice, channel) -------
// R0/R8/R9b/R11-proven body — DO NOT TOUCH: per tri, acc[g] += w3*(p[g]*xv[g][i]).
template <int A0, int A1, bool LIN>
__device__ __forceinline__ void eval_nest(const float (&xv)[GG][NL],
                                          const float4* __restrict__ a3v,
                                          const float2* __restrict__ a2v,
                                          const float* __restrict__ a1p,
                                          float (&acc)[GG]) {
    if (LIN) {
        #pragma unroll
        for (int a = 0; a < NL; a++) {
            float w = a1p[a * CC];
            #pragma unroll
            for (int g = 0; g < GG; g++) acc[g] += w * xv[g][a];
        }
    }
    float4 w4 = {0.f, 0.f, 0.f, 0.f};
    float2 wp = {0.f, 0.f};
    int tri = trisBefore(A0), pr = pairsBefore(A0);
    #pragma unroll
    for (int a = A0; a < A1; a++) {
        #pragma unroll
        for (int b = a; b < NL; b++) {
            float p[GG];
            #pragma unroll
            for (int g = 0; g < GG; g++) p[g] = xv[g][a] * xv[g][b];
            if ((pr & 1) == 0) wp = a2v[(size_t)(pr >> 1) * CC];
            float w2 = ((pr & 1) == 0) ? wp.x : wp.y;
            pr++;
            #pragma unroll
            for (int g = 0; g < GG; g++) acc[g] += w2 * p[g];
            #pragma unroll
            for (int i = b; i < NL; i++) {
                if ((tri & 3) == 0) w4 = a3v[(size_t)(tri >> 2) * CC];
                int r = tri & 3;
                float w3 = (r == 0) ? w4.x : (r == 1) ? w4.y : (r == 2) ? w4.z : w4.w;
                tri++;
                #pragma unroll
                for (int g = 0; g < GG; g++) acc[g] += w3 * (p[g] * xv[g][i]);
            }
        }
    }
}

__global__ __launch_bounds__(CC, 3) void k_main(const float* __restrict__ x,
                                                const float* __restrict__ A3,
                                                const float* __restrict__ A2,
                                                const float* __restrict__ A1,
                                                const int* __restrict__ groups,
                                                const int* __restrict__ ngroups,
                                                float* __restrict__ out) {
    // XCD-chunked bijective swizzle (m204 form): physical blocks round-robin
    // XCDs; give each XCD a contiguous LOGICAL group chunk so its L2 holds the
    // A3 slices of only ~1-2 atom types (groups are type-sorted).
    int pb = blockIdx.x;
    int nb = gridDim.x;
    int q = nb >> 3, r = nb & 7;
    int xcd = pb & 7, sub = pb >> 3;
    int blk = (xcd < r ? xcd * (q + 1) : r * (q + 1) + (xcd - r) * q) + sub;
    if (blk >= *ngroups) return;
    const int* gr = groups + blk * 8;
    int t = gr[0];
    int nvalid = gr[5];
    int c = threadIdx.x;

    int na[GG];
    #pragma unroll
    for (int g = 0; g < GG; g++) na[g] = gr[1 + g];

    float xv[GG][NL];
    #pragma unroll
    for (int g = 0; g < GG; g++)
        #pragma unroll
        for (int i = 0; i < NL; i++)
            xv[g][i] = x[((size_t)na[g] * NL + i) * CC + c];

    const float4* a3v = (const float4*)A3 + (size_t)t * (NTRI / 4) * CC + c;
    const float2* a2v = (const float2*)A2 + (size_t)t * (NPAIR / 2) * CC + c;
    const float* a1p = A1 + (size_t)t * NL * CC + c;

    float acc[GG];
    #pragma unroll
    for (int g = 0; g < GG; g++) acc[g] = 0.f;
    if (blockIdx.y == 0)
        eval_nest<0, S1, true>(xv, a3v, a2v, a1p, acc);
    else if (blockIdx.y == 1)
        eval_nest<S1, S2, false>(xv, a3v, a2v, a1p, acc);
    else
        eval_nest<S2, NL, false>(xv, a3v, a2v, a1p, acc);

    #pragma unroll
    for (int g = 0; g < GG; g++)
        if (g < nvalid) atomicAdd(&out[(size_t)na[g] * CC + c], acc[g]);
}

extern "C" void kernel_launch(void* const* d_in, const int* in_sizes, int n_in,
                              void* d_out, int out_size, void* d_ws, size_t ws_size,
                              hipStream_t stream) {
    const float* x   = (const float*)d_in[0];
    const int* types = (const int*)d_in[1];
    const float* U3  = (const float*)d_in[2];
    const float* U2  = (const float*)d_in[3];
    const float* U1  = (const float*)d_in[4];
    const float* W3  = (const float*)d_in[5];
    const float* W2  = (const float*)d_in[6];
    const float* W1  = (const float*)d_in[7];
    float* out = (float*)d_out;
    int N = in_sizes[1];  // atom count (2048)

    int ngmax = (N + GG - 1) / GG + EE;  // strict upper bound on group count

    float* ws   = (float*)d_ws;
    float* A3   = ws;                           // EE*NTRI*CC (interleaved x4)
    float* A2   = A3 + (size_t)EE * NTRI * CC;  // EE*NPAIR*CC (interleaved x2)
    float* A1   = A2 + (size_t)EE * NPAIR * CC; // EE*NL*CC
    int* buckets = (int*)(A1 + (size_t)EE * NL * CC);  // EE*N
    int* groups  = buckets + (size_t)EE * N;    // ngmax*8
    int* ngroups = groups + (size_t)ngmax * 8;

    hipMemsetAsync(out, 0, (size_t)out_size * sizeof(float), stream);

    constexpr int NB3 = EE * (NTRI / 16);
    constexpr int NB2 = EE * (NPAIR / 8);
    hipLaunchKernelGGL(k_pre, dim3(NB3 + NB2 + EE + 1), dim3(CC), 0, stream,
                       U3, U2, U1, W3, W2, W1, types,
                       A3, A2, A1, buckets, groups, ngroups, N);
    hipLaunchKernelGGL(k_main, dim3(ngmax, 3), dim3(CC), 0, stream,
                       x, A3, A2, A1, groups, ngroups, out);
}

// Round 15
// 106.090 us; speedup vs baseline: 1.0252x; 1.0252x over previous
//
#include <hip/hip_runtime.h>

// MACE symmetric contraction (corr-3), N=2048, NL=16, C=128, E=10, P3=23, P2=4, P1=1.
// out[n,c] = sum_{a<=b<=i} A3[t,tri,c] x_a x_b x_i + sum_{a<=b} A2[t,pr,c] x_a x_b
//          + sum_a A1[t,a,c] x_a,  with A3 = U3sym @ W3[t] etc. (t = atom type).
// R15 = R13 = R11 (session best, 106-107us). FINAL configuration.
// GG=2 (R14b) was neutral-to-negative per the pre-committed rule -> revert.
// Plateau decomposition: ~43us harness poison-fill tax + fixed fills/gaps +
// k_main ~45us latency-bound (VALUBusy 14%, zero scratch, 25MB HBM). All
// levers bounded: eval_nest restructures spill (R3/R4/R7/R10), occupancy
// tweaks neutral (R12/R14), LDS staging infeasible (slice working set up to
// 231KB > 160KB LDS). Session: 127.4 -> 106.1us (-17%).

constexpr int NL = 16;
constexpr int CC = 128;
constexpr int EE = 10;
constexpr int P3 = 23;
constexpr int P2 = 4;
constexpr int P1 = 1;
constexpr int NTRI = 816;   // C(18,3): a<=b<=i from 16
constexpr int NPAIR = 136;  // C(17,2): a<=b from 16
constexpr int GG = 4;       // atoms per group
constexpr int S1 = 4;       // nest split: a in [0,4) | [4,8) | [8,16)
constexpr int S2 = 8;

constexpr int pairsBefore(int a) {
    int s = 0;
    for (int x = 0; x < a; x++) s += NL - x;
    return s;
}
constexpr int trisBefore(int a) {
    int s = 0;
    for (int x = 0; x < a; x++) s += (NL - x) * (NL - x + 1) / 2;
    return s;
}
static_assert(trisBefore(S1) % 4 == 0, "tri split1 must be float4-aligned");
static_assert(pairsBefore(S1) % 2 == 0, "pair split1 must be float2-aligned");
static_assert(trisBefore(S2) % 4 == 0, "tri split2 must be float4-aligned");
static_assert(pairsBefore(S2) % 2 == 0, "pair split2 must be float2-aligned");

// ---------------- Fused precompute + bucketing ----------------
// Block roles: [0, NB3)        A3 build (16 tris each, symU inline via LDS)
//              [NB3, +NB2)     A2 build (8 pairs each, float2-interleaved out)
//              [.., +EE)       A1 build (one type)
//              last block      atom bucketing/grouping
__global__ void k_pre(const float* __restrict__ U3, const float* __restrict__ U2,
                      const float* __restrict__ U1,
                      const float* __restrict__ W3, const float* __restrict__ W2,
                      const float* __restrict__ W1,
                      const int* __restrict__ types,
                      float* __restrict__ A3, float* __restrict__ A2,
                      float* __restrict__ A1,
                      int* __restrict__ buckets, int* __restrict__ groups,
                      int* __restrict__ ngroups, int N) {
    constexpr int TB = 16;                  // tris per A3 block
    constexpr int PB = 8;                   // pairs per A2 block
    constexpr int NB3 = EE * (NTRI / TB);   // 510
    constexpr int NB2 = EE * (NPAIR / PB);  // 170
    __shared__ float u3l[TB * P3];
    __shared__ float u2l[PB * P2];
    __shared__ int scnt[EE];
    __shared__ int goff[EE + 1];
    int b = blockIdx.x;
    int tid = threadIdx.x;

    if (b < NB3) {
        int t = b / (NTRI / TB), tri16 = b % (NTRI / TB);
        for (int idx = tid; idx < TB * P3; idx += blockDim.x) {
            int lt = idx / P3, k = idx % P3;
            int tri = tri16 * TB + lt;
            int rem = tri, a = 0;
            while (rem >= (NL - a) * (NL - a + 1) / 2) { rem -= (NL - a) * (NL - a + 1) / 2; a++; }
            int bb = a;
            while (rem >= NL - bb) { rem -= NL - bb; bb++; }
            int i = bb + rem;
            auto u = [&](int p, int q, int r) { return U3[((p * NL + q) * NL + r) * P3 + k]; };
            float s = u(a,bb,i) + u(a,i,bb) + u(bb,a,i) + u(bb,i,a) + u(i,a,bb) + u(i,bb,a);
            int m = (a == bb && bb == i) ? 6 : ((a == bb || bb == i) ? 2 : 1);
            u3l[idx] = s / (float)m;
        }
        __syncthreads();
        int c = tid;
        float4 sv[TB / 4];
        #pragma unroll
        for (int j = 0; j < TB / 4; j++) sv[j] = {0.f, 0.f, 0.f, 0.f};
        #pragma unroll
        for (int k = 0; k < P3; k++) {
            float w = W3[(t * P3 + k) * CC + c];
            #pragma unroll
            for (int j = 0; j < TB / 4; j++) {
                sv[j].x += u3l[(j * 4 + 0) * P3 + k] * w;
                sv[j].y += u3l[(j * 4 + 1) * P3 + k] * w;
                sv[j].z += u3l[(j * 4 + 2) * P3 + k] * w;
                sv[j].w += u3l[(j * 4 + 3) * P3 + k] * w;
            }
        }
        #pragma unroll
        for (int j = 0; j < TB / 4; j++)
            ((float4*)A3)[((size_t)t * (NTRI / 4) + tri16 * (TB / 4) + j) * CC + c] = sv[j];
    } else if (b < NB3 + NB2) {
        int j = b - NB3;
        int t = j / (NPAIR / PB), pr8 = j % (NPAIR / PB);
        for (int idx = tid; idx < PB * P2; idx += blockDim.x) {
            int lp = idx / P2, k = idx % P2;
            int pr = pr8 * PB + lp;
            int rem = pr, a = 0;
            while (rem >= NL - a) { rem -= NL - a; a++; }
            int bb = a + rem;
            float s = U2[(a * NL + bb) * P2 + k];
            if (a != bb) s += U2[(bb * NL + a) * P2 + k];
            u2l[idx] = s;
        }
        __syncthreads();
        int c = tid;
        float2 sv[PB / 2];
        #pragma unroll
        for (int jj = 0; jj < PB / 2; jj++) sv[jj] = {0.f, 0.f};
        #pragma unroll
        for (int k = 0; k < P2; k++) {
            float w = W2[(t * P2 + k) * CC + c];
            #pragma unroll
            for (int jj = 0; jj < PB / 2; jj++) {
                sv[jj].x += u2l[(jj * 2 + 0) * P2 + k] * w;
                sv[jj].y += u2l[(jj * 2 + 1) * P2 + k] * w;
            }
        }
        #pragma unroll
        for (int jj = 0; jj < PB / 2; jj++)
            ((float2*)A2)[((size_t)t * (NPAIR / 2) + pr8 * (PB / 2) + jj) * CC + c] = sv[jj];
    } else if (b < NB3 + NB2 + EE) {
        int t = b - NB3 - NB2;
        int c = tid;
        #pragma unroll
        for (int a = 0; a < NL; a++) {
            // P1 == 1: A1[t,a,c] = U1[a] * W1[t,0,c]
            A1[((size_t)t * NL + a) * CC + c] = U1[a * P1] * W1[(size_t)t * P1 * CC + c];
        }
    } else {
        // ---- bucketing / grouping (single block) ----
        if (tid < EE) scnt[tid] = 0;
        __syncthreads();
        for (int n = tid; n < N; n += blockDim.x) {
            int t = types[n];
            int pos = atomicAdd(&scnt[t], 1);
            buckets[t * N + pos] = n;
        }
        __syncthreads();
        if (tid == 0) {
            int off = 0;
            for (int t = 0; t < EE; t++) { goff[t] = off; off += (scnt[t] + GG - 1) / GG; }
            goff[EE] = off;
            *ngroups = off;
        }
        __syncthreads();
        for (int t = 0; t < EE; t++) {
            int cnt = scnt[t];
            int ng = (cnt + GG - 1) / GG;
            for (int g = tid; g < ng; g += blockDim.x) {
                int* gr = &groups[(goff[t] + g) * 8];
                int nv = cnt - g * GG; if (nv > GG) nv = GG;
                gr[0] = t;
                gr[5] = nv;
                for (int j = 0; j < GG; j++) {
                    int jj = j < nv ? j : nv - 1;
                    gr[1 + j] = buckets[t * N + g * GG + jj];
                }
            }
        }
    }
}

// ---------------- Main: evaluate cubic form per (group-slice, channel) -------
// R0/R8/R9b/R11-proven body — DO NOT TOUCH: per tri, acc[g] += w3*(p[g]*xv[g][i]).
template <int A0, int A1, bool LIN>
__device__ __forceinline__ void eval_nest(const float (&xv)[GG][NL],
                                          const float4* __restrict__ a3v,
                                          const float2* __restrict__ a2v,
                                          const float* __restrict__ a1p,
                                          float (&acc)[GG]) {
    if (LIN) {
        #pragma unroll
        for (int a = 0; a < NL; a++) {
            float w = a1p[a * CC];
            #pragma unroll
            for (int g = 0; g < GG; g++) acc[g] += w * xv[g][a];
        }
    }
    float4 w4 = {0.f, 0.f, 0.f, 0.f};
    float2 wp = {0.f, 0.f};
    int tri = trisBefore(A0), pr = pairsBefore(A0);
    #pragma unroll
    for (int a = A0; a < A1; a++) {
        #pragma unroll
        for (int b = a; b < NL; b++) {
            float p[GG];
            #pragma unroll
            for (int g = 0; g < GG; g++) p[g] = xv[g][a] * xv[g][b];
            if ((pr & 1) == 0) wp = a2v[(size_t)(pr >> 1) * CC];
            float w2 = ((pr & 1) == 0) ? wp.x : wp.y;
            pr++;
            #pragma unroll
            for (int g = 0; g < GG; g++) acc[g] += w2 * p[g];
            #pragma unroll
            for (int i = b; i < NL; i++) {
                if ((tri & 3) == 0) w4 = a3v[(size_t)(tri >> 2) * CC];
                int r = tri & 3;
                float w3 = (r == 0) ? w4.x : (r == 1) ? w4.y : (r == 2) ? w4.z : w4.w;
                tri++;
                #pragma unroll
                for (int g = 0; g < GG; g++) acc[g] += w3 * (p[g] * xv[g][i]);
            }
        }
    }
}

__global__ __launch_bounds__(CC, 3) void k_main(const float* __restrict__ x,
                                                const float* __restrict__ A3,
                                                const float* __restrict__ A2,
                                                const float* __restrict__ A1,
                                                const int* __restrict__ groups,
                                                const int* __restrict__ ngroups,
                                                float* __restrict__ out) {
    // XCD-chunked bijective swizzle (m204 form): physical blocks round-robin
    // XCDs; give each XCD a contiguous LOGICAL group chunk so its L2 holds the
    // A3 slices of only ~1-2 atom types (groups are type-sorted).
    int pb = blockIdx.x;
    int nb = gridDim.x;
    int q = nb >> 3, r = nb & 7;
    int xcd = pb & 7, sub = pb >> 3;
    int blk = (xcd < r ? xcd * (q + 1) : r * (q + 1) + (xcd - r) * q) + sub;
    if (blk >= *ngroups) return;
    const int* gr = groups + blk * 8;
    int t = gr[0];
    int nvalid = gr[5];
    int c = threadIdx.x;

    int na[GG];
    #pragma unroll
    for (int g = 0; g < GG; g++) na[g] = gr[1 + g];

    float xv[GG][NL];
    #pragma unroll
    for (int g = 0; g < GG; g++)
        #pragma unroll
        for (int i = 0; i < NL; i++)
            xv[g][i] = x[((size_t)na[g] * NL + i) * CC + c];

    const float4* a3v = (const float4*)A3 + (size_t)t * (NTRI / 4) * CC + c;
    const float2* a2v = (const float2*)A2 + (size_t)t * (NPAIR / 2) * CC + c;
    const float* a1p = A1 + (size_t)t * NL * CC + c;

    float acc[GG] = {0.f, 0.f, 0.f, 0.f};
    if (blockIdx.y == 0)
        eval_nest<0, S1, true>(xv, a3v, a2v, a1p, acc);
    else if (blockIdx.y == 1)
        eval_nest<S1, S2, false>(xv, a3v, a2v, a1p, acc);
    else
        eval_nest<S2, NL, false>(xv, a3v, a2v, a1p, acc);

    #pragma unroll
    for (int g = 0; g < GG; g++)
        if (g < nvalid) atomicAdd(&out[(size_t)na[g] * CC + c], acc[g]);
}

extern "C" void kernel_launch(void* const* d_in, const int* in_sizes, int n_in,
                              void* d_out, int out_size, void* d_ws, size_t ws_size,
                              hipStream_t stream) {
    const float* x   = (const float*)d_in[0];
    const int* types = (const int*)d_in[1];
    const float* U3  = (const float*)d_in[2];
    const float* U2  = (const float*)d_in[3];
    const float* U1  = (const float*)d_in[4];
    const float* W3  = (const float*)d_in[5];
    const float* W2  = (const float*)d_in[6];
    const float* W1  = (const float*)d_in[7];
    float* out = (float*)d_out;
    int N = in_sizes[1];  // atom count (2048)

    int ngmax = (N + GG - 1) / GG + EE;  // strict upper bound on group count

    float* ws   = (float*)d_ws;
    float* A3   = ws;                           // EE*NTRI*CC (interleaved x4)
    float* A2   = A3 + (size_t)EE * NTRI * CC;  // EE*NPAIR*CC (interleaved x2)
    float* A1   = A2 + (size_t)EE * NPAIR * CC; // EE*NL*CC
    int* buckets = (int*)(A1 + (size_t)EE * NL * CC);  // EE*N
    int* groups  = buckets + (size_t)EE * N;    // ngmax*8
    int* ngroups = groups + (size_t)ngmax * 8;

    hipMemsetAsync(out, 0, (size_t)out_size * sizeof(float), stream);

    constexpr int NB3 = EE * (NTRI / 16);
    constexpr int NB2 = EE * (NPAIR / 8);
    hipLaunchKernelGGL(k_pre, dim3(NB3 + NB2 + EE + 1), dim3(CC), 0, stream,
                       U3, U2, U1, W3, W2, W1, types,
                       A3, A2, A1, buckets, groups, ngroups, N);
    hipLaunchKernelGGL(k_main, dim3(ngmax, 3), dim3(CC), 0, stream,
                       x, A3, A2, A1, groups, ngroups, out);
}